// Round 7
// baseline (352.063 us; speedup 1.0000x reference)
//
#include <hip/hip_runtime.h>
#include <hip/hip_bf16.h>

#define BM 128
#define BN 64
#define HD 64
#define LQ 2048
// Q pre-scale: 1/sqrt(16) * log2(e) -> scores in log2 domain (max-free softmax)
#define QSCALE 0.360673760222241f

typedef __attribute__((ext_vector_type(8))) short short8;
typedef __attribute__((ext_vector_type(16))) float f32x16;

union U4S8 { uint4 u; short8 s; };

static __device__ __forceinline__ unsigned pk2(float a, float b) {
    union { __hip_bfloat162 h2; unsigned u; } c;
    c.h2 = __float22bfloat162_rn(make_float2(a, b));   // v_cvt_pk_bf16_f32
    return c.u;
}

// octet swizzle for 64-bf16 (128 B) rows: bank-quad rotation, no padding
static __device__ __forceinline__ int swz(int row, int oct) {
    return (((row >> 3) ^ row) & 7) ^ oct;
}

__global__ __launch_bounds__(512, 4)
void fa_fwd(const float* __restrict__ Qg,
            const float* __restrict__ Kg,
            const float* __restrict__ Vg,
            float* __restrict__ Og) {
    // triple-buffered K/V: 3*8KB + 3*8KB = 48K; +512B denom scratch
    __shared__ unsigned char smem[49152 + 512];
    auto SK  = [&](int buf) { return (unsigned short(*)[64])(smem + buf * 8192); };
    auto SVT = [&](int buf) { return (unsigned short(*)[64])(smem + 24576 + buf * 8192); };

    const int t    = threadIdx.x;
    const int w    = t >> 6;            // wave 0..7
    const int lane = t & 63;
    const int h    = lane >> 5;         // half 0..1
    const int l    = lane & 31;
    const int qg   = w & 3;             // q-group (32 rows)
    const int kvh  = w >> 2;            // kv half of the 64-tile

    const int bx  = blockIdx.x;
    const int idx = (bx >> 5) & 7;
    const int qt  = (bx & 256) ? idx : (15 - idx);
    const int bh  = bx & 31;
    const int q0  = qt * BM;

    const size_t base = (size_t)bh * (LQ * HD);
    const float* Kp = Kg + base;
    const float* Vp = Vg + base;

    const int qrow = q0 + qg * 32 + l;

    // ---- Q fragments: load once from global, keep in registers ----
    short8 bq[4];
    {
        const float* qp = Qg + base + (size_t)qrow * HD;
#pragma unroll
        for (int ks = 0; ks < 4; ++ks) {
            const float4 a = *(const float4*)(qp + ks * 16 + h * 8);
            const float4 b = *(const float4*)(qp + ks * 16 + h * 8 + 4);
            U4S8 cv;
            cv.u.x = pk2(a.x * QSCALE, a.y * QSCALE);
            cv.u.y = pk2(a.z * QSCALE, a.w * QSCALE);
            cv.u.z = pk2(b.x * QSCALE, b.y * QSCALE);
            cv.u.w = pk2(b.z * QSCALE, b.w * QSCALE);
            bq[ks] = cv.s;
        }
    }

    // staging decomposition (512 threads, 64x64 tile, 2 passes)
    const int kr   = t >> 4;            // 0..31
    const int kc   = (t & 15) * 4;
    const int ko   = (t & 15) >> 1;
    const int koff = kc & 7;
    const int vl   = lane & 15;
    const int vqd  = (lane >> 4) & 3;

    auto issueS = [&](int kv0, float4* kf, float4* vf) {
        kf[0] = *(const float4*)(Kp + (size_t)(kv0 + kr) * HD + kc);
        kf[1] = *(const float4*)(Kp + (size_t)(kv0 + 32 + kr) * HD + kc);
        vf[0] = *(const float4*)(Vp + (size_t)(kv0 + w * 4 + vqd) * HD + vl * 4);
        vf[1] = *(const float4*)(Vp + (size_t)(kv0 + 32 + w * 4 + vqd) * HD + vl * 4);
    };

    auto commitS = [&](int buf, const float4* kf, const float4* vf) {
#pragma unroll
        for (int p = 0; p < 2; ++p) {
            const int r = p * 32 + kr;
            uint2 u; u.x = pk2(kf[p].x, kf[p].y); u.y = pk2(kf[p].z, kf[p].w);
            *(uint2*)&SK(buf)[r][swz(r, ko) * 8 + koff] = u;
        }
#pragma unroll
        for (int p = 0; p < 2; ++p) {
            float e0 = vf[p].x, e1 = vf[p].y, e2 = vf[p].z, e3 = vf[p].w;
            // 4x4 transpose across quads (validated R2-R6)
            float s0 = (vqd & 2) ? e0 : e2;
            float s1 = (vqd & 2) ? e1 : e3;
            s0 = __shfl_xor(s0, 32); s1 = __shfl_xor(s1, 32);
            if (vqd & 2) { e0 = s0; e1 = s1; } else { e2 = s0; e3 = s1; }
            s0 = (vqd & 1) ? e0 : e1;
            s1 = (vqd & 1) ? e2 : e3;
            s0 = __shfl_xor(s0, 16); s1 = __shfl_xor(s1, 16);
            if (vqd & 1) { e0 = s0; e2 = s1; } else { e1 = s0; e3 = s1; }
            const int d = vl * 4 + vqd;         // V^T row
            const int R = p * 32 + w * 4;       // kv base of the 4 cols
            uint2 u; u.x = pk2(e0, e1); u.y = pk2(e2, e3);
            *(uint2*)&SVT(buf)[d][swz(d, R >> 3) * 8 + (R & 4)] = u;
        }
    };

    f32x16 accO[2];
#pragma unroll
    for (int mt = 0; mt < 2; ++mt)
#pragma unroll
        for (int i = 0; i < 16; ++i) accO[mt][i] = 0.f;
    float lsum = 0.f;

    const int qminw = q0 + qg * 32;
    const int qmaxw = qminw + 31;
    const int n_it  = (q0 + BM) / BN;      // 2*qt + 2 (always even)

    auto body = [&](int it, int buf) {
        const int kv0 = it * BN;
        const int kvb = kv0 + kvh * 32;    // this wave's kv window base
        if (kvb > qmaxw) return;           // wave-uniform skip of masked tiles

        const int row = kvh * 32 + l;
        // ---- S^T = K * Q^T with TWO independent MFMA chains (ILP) ----
        const short8 ak0 = *(const short8*)&SK(buf)[row][swz(row, 0 + h) * 8];
        const short8 ak1 = *(const short8*)&SK(buf)[row][swz(row, 2 + h) * 8];
        const short8 ak2 = *(const short8*)&SK(buf)[row][swz(row, 4 + h) * 8];
        const short8 ak3 = *(const short8*)&SK(buf)[row][swz(row, 6 + h) * 8];
        f32x16 a0, a1;
#pragma unroll
        for (int i = 0; i < 16; ++i) { a0[i] = 0.f; a1[i] = 0.f; }
        a0 = __builtin_amdgcn_mfma_f32_32x32x16_bf16(ak0, bq[0], a0, 0, 0, 0);
        a1 = __builtin_amdgcn_mfma_f32_32x32x16_bf16(ak1, bq[1], a1, 0, 0, 0);
        a0 = __builtin_amdgcn_mfma_f32_32x32x16_bf16(ak2, bq[2], a0, 0, 0, 0);
        a1 = __builtin_amdgcn_mfma_f32_32x32x16_bf16(ak3, bq[3], a1, 0, 0, 0);
        a0 = a0 + a1;                      // merge chains

        // ---- causal mask: kv(reg=4g+r) = kvb + 8g + 4h + r ----
        if (kvb + 31 > qminw) {
#pragma unroll
            for (int g = 0; g < 4; ++g)
#pragma unroll
                for (int r = 0; r < 4; ++r)
                    if (kvb + g * 8 + h * 4 + r > qrow)
                        a0[g * 4 + r] = -1e30f;
        }

        // ---- max-free softmax (log2 domain) ----
#pragma unroll
        for (int i = 0; i < 16; ++i) {
            const float p = __builtin_amdgcn_exp2f(a0[i]);
            a0[i] = p;
            lsum += p;
        }

        // ---- P C-layout -> B-frag in registers (cross-half shfl only) ----
#pragma unroll
        for (int ks = 0; ks < 2; ++ks) {
            const int go = 2 * ks + h;        // block this (ks, h-target) needs
            const int gs = 2 * ks + (1 - h);  // block the partner half needs
            const unsigned o0 = pk2(a0[4 * go + 0], a0[4 * go + 1]);
            const unsigned o1 = pk2(a0[4 * go + 2], a0[4 * go + 3]);
            unsigned s0 = pk2(a0[4 * gs + 0], a0[4 * gs + 1]);
            unsigned s1 = pk2(a0[4 * gs + 2], a0[4 * gs + 3]);
            const unsigned r0 = __shfl_xor(s0, 32);
            const unsigned r1 = __shfl_xor(s1, 32);
            U4S8 fb;
            fb.u.x = h ? r0 : o0;
            fb.u.y = h ? r1 : o1;
            fb.u.z = h ? o0 : r0;
            fb.u.w = h ? o1 : r1;
            // ---- O^T += V^T * P^T (two mt chains of depth 1 per ks) ----
#pragma unroll
            for (int mt = 0; mt < 2; ++mt) {
                const int vrow = mt * 32 + l;
                const short8 av = *(const short8*)
                    &SVT(buf)[vrow][swz(vrow, kvh * 4 + 2 * ks + h) * 8];
                accO[mt] = __builtin_amdgcn_mfma_f32_32x32x16_bf16(av, fb.s, accO[mt], 0, 0, 0);
            }
        }
    };

    // prefetch register sets
    float4 kfA[2], vfA[2], kfB[2], vfB[2];

    // prologue: tile0 -> buf0, tile1 loads in flight (distance-2 pipeline)
    issueS(0, kfA, vfA);
    commitS(0, kfA, vfA);
    issueS(BN, kfB, vfB);

    int b0 = 0;
    for (int it = 0; it < n_it; it += 2) {
        const int b1 = (b0 + 1 == 3) ? 0 : b0 + 1;
        const int b2 = (b1 + 1 == 3) ? 0 : b1 + 1;

        __syncthreads();                        // buf b0 ready
        if (it + 2 < n_it) issueS((it + 2) * BN, kfA, vfA);
        body(it, b0);
        if (it + 1 < n_it) commitS(b1, kfB, vfB);

        __syncthreads();                        // buf b1 ready
        if (it + 3 < n_it) issueS((it + 3) * BN, kfB, vfB);
        body(it + 1, b1);
        if (it + 2 < n_it) commitS(b2, kfA, vfA);

        b0 = b2;
    }

    // ---- epilogue: combine kv-halves (linear: numerators & denoms add) ----
    lsum += __shfl_xor(lsum, 32);
    __syncthreads();                       // all sK/sVt reads done -> overlay
    float (*FL)[64] = (float(*)[64])smem;  // [128][64] fp32 partials (32 KB)
    float* SLS = (float*)(smem + 49152);   // 128 denoms
    if (w >= 4) {
        const int w4 = w & 3;
        SLS[w4 * 32 + l] = lsum;
#pragma unroll
        for (int mt = 0; mt < 2; ++mt)
#pragma unroll
            for (int g = 0; g < 4; ++g) {
                float4 o;
                o.x = accO[mt][g * 4 + 0]; o.y = accO[mt][g * 4 + 1];
                o.z = accO[mt][g * 4 + 2]; o.w = accO[mt][g * 4 + 3];
                *(float4*)&FL[w4 * 32 + l][mt * 32 + g * 8 + h * 4] = o;
            }
    }
    __syncthreads();
    if (w < 4) {
        const float inv = 1.0f / (lsum + SLS[w * 32 + l]);
        float* Op = Og + base + (size_t)qrow * HD;
#pragma unroll
        for (int mt = 0; mt < 2; ++mt)
#pragma unroll
            for (int g = 0; g < 4; ++g) {
                const float4 pv = *(const float4*)&FL[w * 32 + l][mt * 32 + g * 8 + h * 4];
                float4 o;
                o.x = (accO[mt][g * 4 + 0] + pv.x) * inv;
                o.y = (accO[mt][g * 4 + 1] + pv.y) * inv;
                o.z = (accO[mt][g * 4 + 2] + pv.z) * inv;
                o.w = (accO[mt][g * 4 + 3] + pv.w) * inv;
                *(float4*)(Op + mt * 32 + g * 8 + h * 4) = o;   // d = 32mt+8g+4h+r
            }
    }
}

extern "C" void kernel_launch(void* const* d_in, const int* in_sizes, int n_in,
                              void* d_out, int out_size, void* d_ws, size_t ws_size,
                              hipStream_t stream) {
    const float* Q = (const float*)d_in[0];
    const float* K = (const float*)d_in[1];
    const float* V = (const float*)d_in[2];
    float* O = (float*)d_out;
    fa_fwd<<<dim3(512), dim3(512), 0, stream>>>(Q, K, V, O);
}

// Round 8
// 131.063 us; speedup vs baseline: 2.6862x; 2.6862x over previous
//
#include <hip/hip_runtime.h>
#include <hip/hip_bf16.h>

#define BM 128
#define BN 64
#define HD 64
#define LQ 2048
// Q pre-scale: 1/sqrt(16) * log2(e) -> scores in log2 domain (max-free softmax)
#define QSCALE 0.360673760222241f

typedef __attribute__((ext_vector_type(8))) short short8;
typedef __attribute__((ext_vector_type(4))) float f32x4;

static __device__ __forceinline__ unsigned pk2(float a, float b) {
    union { __hip_bfloat162 h2; unsigned u; } c;
    c.h2 = __float22bfloat162_rn(make_float2(a, b));   // v_cvt_pk_bf16_f32
    return c.u;
}

__global__ __launch_bounds__(512, 2)
void fa_fwd(const float* __restrict__ Qg,
            const float* __restrict__ Kg,
            const float* __restrict__ Vg,
            float* __restrict__ Og) {
    // unpadded 64-elem (128 B) rows, XOR-octet swizzled: phys_oct = oct ^ (row&7)
    // reads (b128 frags) conflict-free; writes <=4-way. 48.0 KB -> 3 blocks/CU.
    __shared__ unsigned short sK[2][BN][64];    // [buf][kv][d]
    __shared__ unsigned short sVt[2][HD][64];   // [buf][d][kv]
    __shared__ unsigned short sP[8][16][64];    // [wave][q][kv]

    const int t    = threadIdx.x;
    const int w    = t >> 6;            // wave 0..7 (owns 16 q rows)
    const int lane = t & 63;
    const int qd   = lane >> 4;         // quad 0..3
    const int l    = lane & 15;
    const int l7   = l & 7;

    const int bx  = blockIdx.x;
    const int qt  = 15 - (bx >> 5);     // heavy q-tiles dispatch first
    const int bh  = bx & 31;
    const int q0  = qt * BM;

    const size_t base = (size_t)bh * (LQ * HD);
    const float* Kp = Kg + base;
    const float* Vp = Vg + base;

    const int qrow = q0 + w * 16 + l;

    // ---- Q B-frags: load once from global into registers (sQ eliminated) ----
    // B-frag 16x16x32: B[k=32ks+8qd+j][n=q=l]
    short8 bq[2];
    {
        const float* qp = Qg + base + (size_t)qrow * HD;
#pragma unroll
        for (int ks = 0; ks < 2; ++ks) {
            const float4 a = *(const float4*)(qp + ks * 32 + qd * 8);
            const float4 b = *(const float4*)(qp + ks * 32 + qd * 8 + 4);
            union { short8 s; uint4 u; } cv;
            cv.u.x = pk2(a.x * QSCALE, a.y * QSCALE);
            cv.u.y = pk2(a.z * QSCALE, a.w * QSCALE);
            cv.u.z = pk2(b.x * QSCALE, b.y * QSCALE);
            cv.u.w = pk2(b.z * QSCALE, b.w * QSCALE);
            bq[ks] = cv.s;
        }
    }

    // staging decomposition (512 threads, 64x64 tile)
    const int r0   = t >> 4;            // 0..31
    const int c4   = (t & 15) * 4;      // 0..60
    const int ko   = c4 >> 3;           // d-octet
    const int koff = c4 & 7;            // 0 or 4
    const int RA   = w * 4;             // V kv base within 32-half

    float4 kf[2], vf[2];
    auto issue = [&](int kv0) {
        kf[0] = *(const float4*)(Kp + (size_t)(kv0 + r0) * HD + c4);
        kf[1] = *(const float4*)(Kp + (size_t)(kv0 + 32 + r0) * HD + c4);
        vf[0] = *(const float4*)(Vp + (size_t)(kv0 + RA + qd) * HD + c4);
        vf[1] = *(const float4*)(Vp + (size_t)(kv0 + 32 + RA + qd) * HD + c4);
    };

    auto commit = [&](int buf) {
#pragma unroll
        for (int p = 0; p < 2; ++p) {
            const int r = p * 32 + r0;
            uint2 u; u.x = pk2(kf[p].x, kf[p].y); u.y = pk2(kf[p].z, kf[p].w);
            *(uint2*)&sK[buf][r][((ko ^ (r & 7)) << 3) + koff] = u;
        }
#pragma unroll
        for (int p = 0; p < 2; ++p) {
            float e0 = vf[p].x, e1 = vf[p].y, e2 = vf[p].z, e3 = vf[p].w;
            // 4x4 transpose across quads (validated R2-R7)
            float s0 = (qd & 2) ? e0 : e2;
            float s1 = (qd & 2) ? e1 : e3;
            s0 = __shfl_xor(s0, 32); s1 = __shfl_xor(s1, 32);
            if (qd & 2) { e0 = s0; e1 = s1; } else { e2 = s0; e3 = s1; }
            s0 = (qd & 1) ? e0 : e1;
            s1 = (qd & 1) ? e2 : e3;
            s0 = __shfl_xor(s0, 16); s1 = __shfl_xor(s1, 16);
            if (qd & 1) { e0 = s0; e2 = s1; } else { e1 = s0; e3 = s1; }
            // lane now holds V^T[d = c4+qd][R..R+3], R = p*32 + w*4
            const int d = c4 + qd;
            const int R = p * 32 + RA;
            uint2 u; u.x = pk2(e0, e1); u.y = pk2(e2, e3);
            *(uint2*)&sVt[buf][d][(((R >> 3) ^ (d & 7)) << 3) + (R & 4)] = u;
        }
    };

    f32x4 accO[4];
#pragma unroll
    for (int mt = 0; mt < 4; ++mt) accO[mt] = (f32x4){0.f, 0.f, 0.f, 0.f};
    float lsum = 0.f;

    const int qminw = q0 + w * 16;
    const int qmaxw = qminw + 15;
    const int n_it  = (q0 + BM) / BN;      // 2*qt + 2, block-uniform

    issue(0);
    commit(0);

    for (int it = 0; it < n_it; ++it) {
        const int kv0 = it * BN;
        const int buf = it & 1;
        __syncthreads();                   // buf writes visible; prev reads done
        const bool more = (it + 1 < n_it);
        if (more) issue(kv0 + BN);         // next tile's loads stay in flight

        if (kv0 <= qmaxw) {                // wave-uniform skip of masked tiles
            // ---- S^T = K * Q^T : 4 mt x 2 ks, conflict-free frag reads ----
            f32x4 accS[4];
#pragma unroll
            for (int mt = 0; mt < 4; ++mt) accS[mt] = (f32x4){0.f, 0.f, 0.f, 0.f};
#pragma unroll
            for (int ks = 0; ks < 2; ++ks) {
#pragma unroll
                for (int mt = 0; mt < 4; ++mt) {
                    const int row = mt * 16 + l;
                    const short8 ak = *(const short8*)
                        &sK[buf][row][(((ks * 4 + qd) ^ l7)) << 3];
                    accS[mt] = __builtin_amdgcn_mfma_f32_16x16x32_bf16(ak, bq[ks], accS[mt], 0, 0, 0);
                }
            }

            // ---- causal mask (diagonal-straddling tiles only) ----
            if (kv0 + BN - 1 > qminw) {
#pragma unroll
                for (int mt = 0; mt < 4; ++mt) {
                    const int kvr = kv0 + mt * 16 + qd * 4;
#pragma unroll
                    for (int r = 0; r < 4; ++r)
                        if (kvr + r > qrow) accS[mt][r] = -1e30f;
                }
            }

            // ---- max-free softmax (log2 domain), pack P -> LDS ----
#pragma unroll
            for (int mt = 0; mt < 4; ++mt) {
                const float p0 = __builtin_amdgcn_exp2f(accS[mt][0]);
                const float p1 = __builtin_amdgcn_exp2f(accS[mt][1]);
                const float p2 = __builtin_amdgcn_exp2f(accS[mt][2]);
                const float p3 = __builtin_amdgcn_exp2f(accS[mt][3]);
                lsum += (p0 + p1) + (p2 + p3);
                uint2 u; u.x = pk2(p0, p1); u.y = pk2(p2, p3);
                const int oct = 2 * mt + (qd >> 1);
                *(uint2*)&sP[w][l][((oct ^ l7) << 3) + ((qd & 1) << 2)] = u;
            }
            asm volatile("s_waitcnt lgkmcnt(0)" ::: "memory");  // per-wave region

            // ---- O^T += V^T * P^T : 4 mt x 2 ks ----
#pragma unroll
            for (int ks = 0; ks < 2; ++ks) {
                const short8 bp = *(const short8*)
                    &sP[w][l][(((ks * 4 + qd) ^ l7)) << 3];
#pragma unroll
                for (int mt = 0; mt < 4; ++mt) {
                    const int row = mt * 16 + l;
                    const short8 av = *(const short8*)
                        &sVt[buf][row][(((ks * 4 + qd) ^ l7)) << 3];
                    accO[mt] = __builtin_amdgcn_mfma_f32_16x16x32_bf16(av, bp, accO[mt], 0, 0, 0);
                }
            }
        }

        if (more) commit(buf ^ 1);         // convert prefetched regs -> other buffer
    }

    // ---- epilogue: reduce denom across the 4 replica lanes, write O ----
    lsum += __shfl_xor(lsum, 16);
    lsum += __shfl_xor(lsum, 32);
    const float inv = 1.0f / lsum;
    float* Op = Og + base + (size_t)qrow * HD;
#pragma unroll
    for (int mt = 0; mt < 4; ++mt) {
        float4 o;
        o.x = accO[mt][0] * inv; o.y = accO[mt][1] * inv;
        o.z = accO[mt][2] * inv; o.w = accO[mt][3] * inv;
        *(float4*)(Op + mt * 16 + qd * 4) = o;   // d = 16*mt + 4*quad + reg
    }
}

extern "C" void kernel_launch(void* const* d_in, const int* in_sizes, int n_in,
                              void* d_out, int out_size, void* d_ws, size_t ws_size,
                              hipStream_t stream) {
    const float* Q = (const float*)d_in[0];
    const float* K = (const float*)d_in[1];
    const float* V = (const float*)d_in[2];
    float* O = (float*)d_out;
    fa_fwd<<<dim3(512), dim3(512), 0, stream>>>(Q, K, V, O);
}